// Round 7
// baseline (372.893 us; speedup 1.0000x reference)
//
#include <hip/hip_runtime.h>
#include <cstdint>

static constexpr int M = 16384;   // B*N rows
static constexpr int D = 768;     // feature dim
static constexpr int E = 32;      // code dim
static constexpr int K = 8192;    // codebook size

typedef _Float16 half8 __attribute__((ext_vector_type(8)));
typedef float f32x4 __attribute__((ext_vector_type(4)));

// ---------------- Pre-pass: W1 [768k][768n] fp32 -> W1aT/W1bT [768n][768k] fp16 ----------------
__global__ __launch_bounds__(256) void split_w1t(const float* __restrict__ W1,
    _Float16* __restrict__ W1aT, _Float16* __restrict__ W1bT)
{
  __shared__ float tile[32][33];
  const int tx = threadIdx.x & 31, ty = threadIdx.x >> 5;
  const int kb = blockIdx.x * 32, nb = blockIdx.y * 32;
#pragma unroll
  for (int i = 0; i < 4; ++i)
    tile[ty * 4 + i][tx] = W1[(size_t)(kb + ty * 4 + i) * 768 + nb + tx];
  __syncthreads();
#pragma unroll
  for (int i = 0; i < 4; ++i) {
    const int n = nb + ty * 4 + i, k = kb + tx;
    const float v = tile[tx][ty * 4 + i] * 64.0f;
    const _Float16 h = (_Float16)v;
    W1aT[(size_t)n * 768 + k] = h;
    W1bT[(size_t)n * 768 + k] = (_Float16)((v - (float)h) * 4096.0f);
  }
}

// ---------------- Pre-pass: W2 [768k][32n] fp32 -> W2Th/W2Tr [32n][768k] fp16 ----------------
__global__ __launch_bounds__(256) void split_w2t(const float* __restrict__ W2,
    _Float16* __restrict__ W2Th, _Float16* __restrict__ W2Tr)
{
  const int i = blockIdx.x * 256 + threadIdx.x;   // 24576 total
  const int k = i >> 5, n = i & 31;
  const float v = W2[(size_t)k * 32 + n] * 64.0f;
  const _Float16 h = (_Float16)v;
  W2Th[(size_t)n * 768 + k] = h;
  W2Tr[(size_t)n * 768 + k] = (_Float16)((v - (float)h) * 4096.0f);
}

// ---------------- Pre-pass: codebook -> cc norms + f16 hi/res split ----------------
__global__ __launch_bounds__(256) void cb_prep(const float* __restrict__ CB,
    float* __restrict__ cc, _Float16* __restrict__ CBh, _Float16* __restrict__ CBr)
{
  const int k = blockIdx.x * 256 + threadIdx.x;
  const float4* p = (const float4*)(CB + (size_t)k * E);
  _Float16 hb[32], rb[32];
  float s = 0.f;
#pragma unroll
  for (int q = 0; q < 8; ++q) {
    float4 v = p[q];
    const float e[4] = {v.x, v.y, v.z, v.w};
#pragma unroll
    for (int j = 0; j < 4; ++j) {
      s += e[j] * e[j];
      const _Float16 h = (_Float16)e[j];
      hb[q * 4 + j] = h;
      rb[q * 4 + j] = (_Float16)((e[j] - (float)h) * 4096.0f);
    }
  }
  cc[k] = s;
#pragma unroll
  for (int q = 0; q < 4; ++q) {
    *(half8*)(CBh + (size_t)k * E + q * 8) = *(half8*)&hb[q * 8];
    *(half8*)(CBr + (size_t)k * E + q * 8) = *(half8*)&rb[q * 8];
  }
}

// ---------------- Kernel A: H1 = tanh(X @ W1 + b1), LDS-free direct-fragment MFMA ----------------
// Wave = 32 rows x 64 cols (2 m-tiles x 4 n-tiles); block = 4 waves stacked in m (128 rows).
// Grid (12 col-tiles, 128 row-tiles), col-fastest so X row-panels stay L2/L3-hot.
// Math (split constants, per-k-step MFMA order) identical to rounds 4-6 -> H1 bit-identical.
__global__ __launch_bounds__(256, 2) void gemm1_mfma(
    const float* __restrict__ X, const _Float16* __restrict__ Bag,
    const _Float16* __restrict__ Bbg, const float* __restrict__ bias,
    float* __restrict__ C)
{
  const int t = threadIdx.x;
  const int lane = t & 63, wave = t >> 6;
  const int rowBase = blockIdx.y * 128 + wave * 32;
  const int colBase = blockIdx.x * 64;
  const int col = lane & 15;       // fragment row-select
  const int kg = lane >> 4;        // k-group (8 elems)

  const float* Xp0 = X + (size_t)(rowBase + col) * D + kg * 8;
  const float* Xp1 = X + (size_t)(rowBase + 16 + col) * D + kg * 8;
  const _Float16* BhP[4];
  const _Float16* BrP[4];
#pragma unroll
  for (int fn = 0; fn < 4; ++fn) {
    BhP[fn] = Bag + (size_t)(colBase + fn * 16 + col) * D + kg * 8;
    BrP[fn] = Bbg + (size_t)(colBase + fn * 16 + col) * D + kg * 8;
  }

  f32x4 accM[2][4], accR[2][4];
  const f32x4 z4 = {0.f, 0.f, 0.f, 0.f};
#pragma unroll
  for (int i = 0; i < 2; ++i)
#pragma unroll
    for (int j = 0; j < 4; ++j) { accM[i][j] = z4; accR[i][j] = z4; }

#pragma unroll 3
  for (int ks = 0; ks < 24; ++ks) {
    const int ko = ks * 32;
    half8 bA[4], bB[4];
#pragma unroll
    for (int fn = 0; fn < 4; ++fn) {
      bA[fn] = *(const half8*)(BhP[fn] + ko);
      bB[fn] = *(const half8*)(BrP[fn] + ko);
    }
    half8 aA[2], aB[2];
    {
      const float4 x00 = *(const float4*)(Xp0 + ko);
      const float4 x01 = *(const float4*)(Xp0 + ko + 4);
      const float4 x10 = *(const float4*)(Xp1 + ko);
      const float4 x11 = *(const float4*)(Xp1 + ko + 4);
      const float v0[8] = {x00.x, x00.y, x00.z, x00.w, x01.x, x01.y, x01.z, x01.w};
      const float v1[8] = {x10.x, x10.y, x10.z, x10.w, x11.x, x11.y, x11.z, x11.w};
#pragma unroll
      for (int e = 0; e < 8; ++e) {
        _Float16 h0 = (_Float16)v0[e];
        aA[0][e] = h0;
        aB[0][e] = (_Float16)((v0[e] - (float)h0) * 4096.0f);
        _Float16 h1 = (_Float16)v1[e];
        aA[1][e] = h1;
        aB[1][e] = (_Float16)((v1[e] - (float)h1) * 4096.0f);
      }
    }
#pragma unroll
    for (int fm = 0; fm < 2; ++fm)
#pragma unroll
      for (int fn = 0; fn < 4; ++fn) {
        accM[fm][fn] = __builtin_amdgcn_mfma_f32_16x16x32_f16(aA[fm], bA[fn], accM[fm][fn], 0, 0, 0);
        accR[fm][fn] = __builtin_amdgcn_mfma_f32_16x16x32_f16(aB[fm], bA[fn], accR[fm][fn], 0, 0, 0);
        accR[fm][fn] = __builtin_amdgcn_mfma_f32_16x16x32_f16(aA[fm], bB[fn], accR[fm][fn], 0, 0, 0);
      }
  }

  // epilogue: C/D row = kg*4 + r, col = lane&15 (same as rounds 4-6)
#pragma unroll
  for (int fm = 0; fm < 2; ++fm) {
    const int mb = rowBase + fm * 16 + kg * 4;
#pragma unroll
    for (int fn = 0; fn < 4; ++fn) {
      const int n = colBase + fn * 16 + col;
      const float bv = bias[n];
#pragma unroll
      for (int r = 0; r < 4; ++r) {
        const float val = accM[fm][fn][r] * 0.015625f
                        + accR[fm][fn][r] * 3.814697265625e-6f + bv;
        C[(size_t)(mb + r) * D + n] = tanhf(val);
      }
    }
  }
}

// ---------------- Kernel B: Z = l2norm(H1 @ W2 + b2), LDS-free direct-fragment MFMA ----------------
// Wave = 16 rows x 32 cols (E). Block = 4 waves = 64 rows; grid 256 blocks.
__global__ __launch_bounds__(256) void gemm2_mfma(
    const float* __restrict__ H, const _Float16* __restrict__ W2Th,
    const _Float16* __restrict__ W2Tr, const float* __restrict__ b2,
    float* __restrict__ Z)
{
  const int t = threadIdx.x;
  const int lane = t & 63, wave = t >> 6;
  const int rowBase = blockIdx.x * 64 + wave * 16;
  const int col = lane & 15;
  const int kg = lane >> 4;

  const float* Hp = H + (size_t)(rowBase + col) * D + kg * 8;
  const _Float16* WhP[2];
  const _Float16* WrP[2];
#pragma unroll
  for (int fn = 0; fn < 2; ++fn) {
    WhP[fn] = W2Th + (size_t)(fn * 16 + col) * D + kg * 8;
    WrP[fn] = W2Tr + (size_t)(fn * 16 + col) * D + kg * 8;
  }

  f32x4 accM[2], accR[2];
  const f32x4 z4 = {0.f, 0.f, 0.f, 0.f};
  accM[0] = z4; accM[1] = z4; accR[0] = z4; accR[1] = z4;

#pragma unroll 3
  for (int ks = 0; ks < 24; ++ks) {
    const int ko = ks * 32;
    half8 wA[2], wB[2];
#pragma unroll
    for (int fn = 0; fn < 2; ++fn) {
      wA[fn] = *(const half8*)(WhP[fn] + ko);
      wB[fn] = *(const half8*)(WrP[fn] + ko);
    }
    half8 hA, hB;
    {
      const float4 x0 = *(const float4*)(Hp + ko);
      const float4 x1 = *(const float4*)(Hp + ko + 4);
      const float v[8] = {x0.x, x0.y, x0.z, x0.w, x1.x, x1.y, x1.z, x1.w};
#pragma unroll
      for (int e = 0; e < 8; ++e) {
        const _Float16 h = (_Float16)v[e];
        hA[e] = h;
        hB[e] = (_Float16)((v[e] - (float)h) * 4096.0f);
      }
    }
#pragma unroll
    for (int fn = 0; fn < 2; ++fn) {
      accM[fn] = __builtin_amdgcn_mfma_f32_16x16x32_f16(hA, wA[fn], accM[fn], 0, 0, 0);
      accR[fn] = __builtin_amdgcn_mfma_f32_16x16x32_f16(hB, wA[fn], accR[fn], 0, 0, 0);
      accR[fn] = __builtin_amdgcn_mfma_f32_16x16x32_f16(hA, wB[fn], accR[fn], 0, 0, 0);
    }
  }

  const float b0 = b2[col], b1 = b2[col + 16];
  float v0[4], v1[4];
#pragma unroll
  for (int r = 0; r < 4; ++r) {
    v0[r] = accM[0][r] * 0.015625f + accR[0][r] * 3.814697265625e-6f + b0;
    v1[r] = accM[1][r] * 0.015625f + accR[1][r] * 3.814697265625e-6f + b1;
  }
#pragma unroll
  for (int r = 0; r < 4; ++r) {
    float ss = v0[r] * v0[r] + v1[r] * v1[r];
    ss += __shfl_xor(ss, 1, 16);
    ss += __shfl_xor(ss, 2, 16);
    ss += __shfl_xor(ss, 4, 16);
    ss += __shfl_xor(ss, 8, 16);
    const float inv = 1.0f / fmaxf(sqrtf(ss), 1e-12f);
    const int row = rowBase + kg * 4 + r;
    Z[(size_t)row * E + col]      = v0[r] * inv;
    Z[(size_t)row * E + col + 16] = v1[r] * inv;
  }
}

// ---------------- Kernel C: VQ argmin via MFMA + gather + STE + per-row loss ----------------
__global__ __launch_bounds__(512) void vq_mfma(
    const float* __restrict__ Z, const float* __restrict__ CB,
    const _Float16* __restrict__ CBh, const _Float16* __restrict__ CBr,
    const float* __restrict__ ccg, float* __restrict__ zq_out,
    float* __restrict__ idx_out, float* __restrict__ lossp)
{
  __shared__ float bDs[64][4];
  __shared__ int   bIs[64][4];

  const int t = threadIdx.x;
  const int lane = t & 63, wave = t >> 6;
  const int mh = wave & 1;
  const int cq = wave >> 1;
  const int rowBase = blockIdx.x * 64;
  const int col = lane & 15, kg = lane >> 4;

  half8 zh[2], zr[2];
#pragma unroll
  for (int mt = 0; mt < 2; ++mt) {
    const float* zp = Z + (size_t)(rowBase + mh * 32 + mt * 16 + col) * E + kg * 8;
    const float4 a = *(const float4*)zp;
    const float4 b = *(const float4*)(zp + 4);
    const float v[8] = {a.x, a.y, a.z, a.w, b.x, b.y, b.z, b.w};
#pragma unroll
    for (int e = 0; e < 8; ++e) {
      const _Float16 h = (_Float16)v[e];
      zh[mt][e] = h;
      zr[mt][e] = (_Float16)((v[e] - (float)h) * 4096.0f);
    }
  }

  const f32x4 zero4 = {0.f, 0.f, 0.f, 0.f};
  float best[2][4];
  int bi[2][4];
#pragma unroll
  for (int mt = 0; mt < 2; ++mt)
#pragma unroll
    for (int r = 0; r < 4; ++r) { best[mt][r] = 3.4e38f; bi[mt][r] = 0; }

  const _Float16* ph = CBh + ((size_t)(cq * 2048 + col) * E + kg * 8);
  const _Float16* pr = CBr + ((size_t)(cq * 2048 + col) * E + kg * 8);
  const float* pc = ccg + cq * 2048 + col;
  int curIdx = cq * 2048 + col;

  for (int tt = 0; tt < 128; ++tt) {
    const half8 bh = *(const half8*)ph;
    const half8 br = *(const half8*)pr;
    const float ccv = *pc;
    ph += 16 * E; pr += 16 * E; pc += 16;
#pragma unroll
    for (int mt = 0; mt < 2; ++mt) {
      f32x4 aM = __builtin_amdgcn_mfma_f32_16x16x32_f16(zh[mt], bh, zero4, 0, 0, 0);
      f32x4 aR = __builtin_amdgcn_mfma_f32_16x16x32_f16(zr[mt], bh, zero4, 0, 0, 0);
      aR = __builtin_amdgcn_mfma_f32_16x16x32_f16(zh[mt], br, aR, 0, 0, 0);
#pragma unroll
      for (int r = 0; r < 4; ++r) {
        const float u = fmaf(aR[r], 2.44140625e-4f, aM[r]);
        const float d = fmaf(u, -2.0f, ccv);
        if (d < best[mt][r]) { best[mt][r] = d; bi[mt][r] = curIdx; }
      }
    }
    curIdx += 16;
  }

#pragma unroll
  for (int m = 1; m <= 8; m <<= 1) {
#pragma unroll
    for (int mt = 0; mt < 2; ++mt)
#pragma unroll
      for (int r = 0; r < 4; ++r) {
        const float ob = __shfl_xor(best[mt][r], m, 64);
        const int   oi = __shfl_xor(bi[mt][r],   m, 64);
        if (ob < best[mt][r] || (ob == best[mt][r] && oi < bi[mt][r])) {
          best[mt][r] = ob; bi[mt][r] = oi;
        }
      }
  }

  if (col == 0) {
#pragma unroll
    for (int mt = 0; mt < 2; ++mt)
#pragma unroll
      for (int r = 0; r < 4; ++r) {
        const int rl = mh * 32 + mt * 16 + kg * 4 + r;
        bDs[rl][cq] = best[mt][r];
        bIs[rl][cq] = bi[mt][r];
      }
  }
  __syncthreads();

  const int rl = t >> 3, part = t & 7;
  float bd = bDs[rl][0];
  int bidx = bIs[rl][0];
#pragma unroll
  for (int q = 1; q < 4; ++q)
    if (bDs[rl][q] < bd) { bd = bDs[rl][q]; bidx = bIs[rl][q]; }

  const int row = rowBase + rl;
  const float4 c4 = *(const float4*)&CB[(size_t)bidx * E + part * 4];
  const float4 z4 = *(const float4*)&Z[(size_t)row * E + part * 4];
  const float dx = c4.x - z4.x, dy = c4.y - z4.y;
  const float dz = c4.z - z4.z, dw = c4.w - z4.w;
  *(float4*)&zq_out[(size_t)row * E + part * 4] =
      make_float4(z4.x + dx, z4.y + dy, z4.z + dz, z4.w + dw);
  float ls = dx * dx;
  ls += dy * dy; ls += dz * dz; ls += dw * dw;
  ls += __shfl_xor(ls, 1, 8);
  ls += __shfl_xor(ls, 2, 8);
  ls += __shfl_xor(ls, 4, 8);
  if (part == 0) {
    lossp[row] = ls;
    idx_out[row] = (float)bidx;
  }
}

// ---------------- Kernel D: loss = sum(lossp) / (M*E) ----------------
__global__ __launch_bounds__(256) void loss_reduce(const float* __restrict__ lossp, float* __restrict__ out)
{
  float s = 0.f;
  const float4* p = reinterpret_cast<const float4*>(lossp);
  for (int i = threadIdx.x; i < M / 4; i += 256) {
    float4 v = p[i];
    s += v.x + v.y + v.z + v.w;
  }
#pragma unroll
  for (int m = 32; m >= 1; m >>= 1) s += __shfl_xor(s, m, 64);
  __shared__ float red[4];
  if ((threadIdx.x & 63) == 0) red[threadIdx.x >> 6] = s;
  __syncthreads();
  if (threadIdx.x == 0)
    out[0] = (red[0] + red[1] + red[2] + red[3]) * (1.0f / (float)(M * E));
}

extern "C" void kernel_launch(void* const* d_in, const int* in_sizes, int n_in,
                              void* d_out, int out_size, void* d_ws, size_t ws_size,
                              hipStream_t stream)
{
  const float* X  = (const float*)d_in[0];
  const float* W1 = (const float*)d_in[1];
  const float* b1 = (const float*)d_in[2];
  const float* W2 = (const float*)d_in[3];
  const float* b2 = (const float*)d_in[4];
  const float* CB = (const float*)d_in[5];

  float* out  = (float*)d_out;
  float* zq   = out;
  float* loss = out + 524288;
  float* idxf = out + 524289;

  char* ws = (char*)d_ws;
  float* H1 = (float*)ws;                                  // 48 MB
  float* Z  = (float*)(ws + (size_t)M * D * 4);            // 2 MB
  float* cc = Z + (size_t)M * E;                           // 32 KB
  float* lp = cc + K;                                      // 64 KB
  _Float16* W1aT = (_Float16*)(lp + M);                    // 1.125 MB
  _Float16* W1bT = W1aT + (size_t)D * D;                   // 1.125 MB
  _Float16* CBh  = W1bT + (size_t)D * D;                   // 512 KB
  _Float16* CBr  = CBh + (size_t)K * E;                    // 512 KB
  _Float16* W2Th = CBr + (size_t)K * E;                    // 48 KB
  _Float16* W2Tr = W2Th + (size_t)E * D;                   // 48 KB

  split_w1t<<<dim3(D / 32, D / 32), 256, 0, stream>>>(W1, W1aT, W1bT);
  split_w2t<<<dim3(D * E / 256), 256, 0, stream>>>(W2, W2Th, W2Tr);
  cb_prep<<<dim3(K / 256), 256, 0, stream>>>(CB, cc, CBh, CBr);
  gemm1_mfma<<<dim3(D / 64, M / 128), 256, 0, stream>>>(X, W1aT, W1bT, b1, H1);
  gemm2_mfma<<<dim3(M / 64), 256, 0, stream>>>(H1, W2Th, W2Tr, b2, Z);
  vq_mfma<<<dim3(M / 64), 512, 0, stream>>>(Z, CB, CBh, CBr, cc, zq, idxf, lp);
  loss_reduce<<<1, 256, 0, stream>>>(lp, loss);
}

// Round 8
// 296.655 us; speedup vs baseline: 1.2570x; 1.2570x over previous
//
#include <hip/hip_runtime.h>
#include <cstdint>

static constexpr int M = 16384;   // B*N rows
static constexpr int D = 768;     // feature dim
static constexpr int E = 32;      // code dim
static constexpr int K = 8192;    // codebook size

typedef _Float16 half8 __attribute__((ext_vector_type(8)));
typedef float f32x4 __attribute__((ext_vector_type(4)));

typedef __attribute__((address_space(1))) const uint32_t gu32;
typedef __attribute__((address_space(3))) uint32_t lu32;
__device__ __forceinline__ void g2l16(const void* g, void* l) {
  __builtin_amdgcn_global_load_lds((gu32*)g, (lu32*)l, 16, 0, 0);
}

// ---------------- Pre-pass: W1 [768k][768n] fp32 -> W1aT/W1bT [768n][768k] fp16 ----------------
__global__ __launch_bounds__(256) void split_w1t(const float* __restrict__ W1,
    _Float16* __restrict__ W1aT, _Float16* __restrict__ W1bT)
{
  __shared__ float tile[32][33];
  const int tx = threadIdx.x & 31, ty = threadIdx.x >> 5;
  const int kb = blockIdx.x * 32, nb = blockIdx.y * 32;
#pragma unroll
  for (int i = 0; i < 4; ++i)
    tile[ty * 4 + i][tx] = W1[(size_t)(kb + ty * 4 + i) * 768 + nb + tx];
  __syncthreads();
#pragma unroll
  for (int i = 0; i < 4; ++i) {
    const int n = nb + ty * 4 + i, k = kb + tx;
    const float v = tile[tx][ty * 4 + i] * 64.0f;
    const _Float16 h = (_Float16)v;
    W1aT[(size_t)n * 768 + k] = h;
    W1bT[(size_t)n * 768 + k] = (_Float16)((v - (float)h) * 4096.0f);
  }
}

// ---------------- Pre-pass: W2 [768k][32n] fp32 -> W2Th/W2Tr [32n][768k] fp16 ----------------
__global__ __launch_bounds__(256) void split_w2t(const float* __restrict__ W2,
    _Float16* __restrict__ W2Th, _Float16* __restrict__ W2Tr)
{
  const int i = blockIdx.x * 256 + threadIdx.x;
  const int k = i >> 5, n = i & 31;
  const float v = W2[(size_t)k * 32 + n] * 64.0f;
  const _Float16 h = (_Float16)v;
  W2Th[(size_t)n * 768 + k] = h;
  W2Tr[(size_t)n * 768 + k] = (_Float16)((v - (float)h) * 4096.0f);
}

// ---------------- Pre-pass: codebook -> cc norms + f16 hi/res split ----------------
__global__ __launch_bounds__(256) void cb_prep(const float* __restrict__ CB,
    float* __restrict__ cc, _Float16* __restrict__ CBh, _Float16* __restrict__ CBr)
{
  const int k = blockIdx.x * 256 + threadIdx.x;
  const float4* p = (const float4*)(CB + (size_t)k * E);
  _Float16 hb[32], rb[32];
  float s = 0.f;
#pragma unroll
  for (int q = 0; q < 8; ++q) {
    float4 v = p[q];
    const float e[4] = {v.x, v.y, v.z, v.w};
#pragma unroll
    for (int j = 0; j < 4; ++j) {
      s += e[j] * e[j];
      const _Float16 h = (_Float16)e[j];
      hb[q * 4 + j] = h;
      rb[q * 4 + j] = (_Float16)((e[j] - (float)h) * 4096.0f);
    }
  }
  cc[k] = s;
#pragma unroll
  for (int q = 0; q < 4; ++q) {
    *(half8*)(CBh + (size_t)k * E + q * 8) = *(half8*)&hb[q * 8];
    *(half8*)(CBr + (size_t)k * E + q * 8) = *(half8*)&rb[q * 8];
  }
}

// ---------------- Kernel A: H1 = tanh(X @ W1 + b1) ----------------
// 128x128 tile, 4 waves (2x2 of 64x64). X fp32 staged via global_load_lds with
// 8-slot XOR source-swizzle (conflict-free ds_read_b128); split to f16 hi/res
// in-reg; B (W1 splits, 2.25MB L2-resident) read direct from global.
// MFMA order per acc identical to rounds 4-7 -> H1 bit-identical.
__global__ __launch_bounds__(256, 2) void gemm1_mfma(
    const float* __restrict__ X, const _Float16* __restrict__ Bag,
    const _Float16* __restrict__ Bbg, const float* __restrict__ bias,
    float* __restrict__ C)
{
  __shared__ __align__(16) float Xs[2][128 * 32];   // 16KB per buffer

  const int t = threadIdx.x;
  const int lane = t & 63, wave = t >> 6;
  const int wm = wave >> 1, wn = wave & 1;
  const int rowBase = blockIdx.y * 128;
  const int colBase = blockIdx.x * 128;
  const int col = lane & 15;     // fragment row-select
  const int kg = lane >> 4;      // k-group

  // staging: 1024 units of 16B (128 rows x 8 slots); 4 g2l16 per thread.
  // source slot pre-swizzled: content(row, s) = X[row][ (s ^ (row&7)) *4 ..+4 ]
  const float* srcB[4];
  int dstOff[4];   // bytes into Xs buffer (wave-uniform base; lane adds lane*16)
#pragma unroll
  for (int i = 0; i < 4; ++i) {
    const int u = t + i * 256;
    const int row = u >> 3, slotL = u & 7;
    const int srcSlot = slotL ^ (row & 7);
    srcB[i] = X + (size_t)(rowBase + row) * D + srcSlot * 4;
    dstOff[i] = (i * 256 + wave * 64) * 16;   // uniform per wave
  }

  const _Float16* BhP[4];
  const _Float16* BrP[4];
#pragma unroll
  for (int fn = 0; fn < 4; ++fn) {
    const int cb = colBase + wn * 64 + fn * 16 + col;
    BhP[fn] = Bag + (size_t)cb * D + kg * 8;
    BrP[fn] = Bbg + (size_t)cb * D + kg * 8;
  }

  // A fragment read offsets (bytes): row r, slots s0=(2kg)^(r&7), s1=(2kg+1)^(r&7)
  const int swz = lane & 7;   // == r&7 for all fm (fm*16, wm*64 are mult of 8)
  int aOff0[4], aOff1[4];
#pragma unroll
  for (int fm = 0; fm < 4; ++fm) {
    const int r = wm * 64 + fm * 16 + col;
    aOff0[fm] = r * 128 + ((2 * kg) ^ swz) * 16;
    aOff1[fm] = r * 128 + ((2 * kg + 1) ^ swz) * 16;
  }

  f32x4 accM[4][4], accR[4][4];
  const f32x4 z4 = {0.f, 0.f, 0.f, 0.f};
#pragma unroll
  for (int i = 0; i < 4; ++i)
#pragma unroll
    for (int j = 0; j < 4; ++j) { accM[i][j] = z4; accR[i][j] = z4; }

  { // prologue: stage ks=0 into buf0
#pragma unroll
    for (int i = 0; i < 4; ++i)
      g2l16(srcB[i], (char*)&Xs[0][0] + dstOff[i]);
    __syncthreads();
  }

  for (int ks = 0; ks < 24; ++ks) {
    const int cur = ks & 1;
    const int ko = ks * 32;
    if (ks < 23) {
      const int k1 = (ks + 1) * 32;
#pragma unroll
      for (int i = 0; i < 4; ++i)
        g2l16(srcB[i] + k1, (char*)&Xs[cur ^ 1][0] + dstOff[i]);
    }
    // B fragments (global, L2-hot)
    half8 bA[4], bB[4];
#pragma unroll
    for (int fn = 0; fn < 4; ++fn) {
      bA[fn] = *(const half8*)(BhP[fn] + ko);
      bB[fn] = *(const half8*)(BrP[fn] + ko);
    }
    // A fragments: ds_read fp32 + in-reg split, then MFMA (same per-acc order)
    const char* base = (const char*)&Xs[cur][0];
#pragma unroll
    for (int fm = 0; fm < 4; ++fm) {
      const float4 fa = *(const float4*)(base + aOff0[fm]);
      const float4 fb = *(const float4*)(base + aOff1[fm]);
      const float v[8] = {fa.x, fa.y, fa.z, fa.w, fb.x, fb.y, fb.z, fb.w};
      half8 aA, aB;
#pragma unroll
      for (int e = 0; e < 8; ++e) {
        const _Float16 h = (_Float16)v[e];
        aA[e] = h;
        aB[e] = (_Float16)((v[e] - (float)h) * 4096.0f);
      }
#pragma unroll
      for (int fn = 0; fn < 4; ++fn) {
        accM[fm][fn] = __builtin_amdgcn_mfma_f32_16x16x32_f16(aA, bA[fn], accM[fm][fn], 0, 0, 0);
        accR[fm][fn] = __builtin_amdgcn_mfma_f32_16x16x32_f16(aB, bA[fn], accR[fm][fn], 0, 0, 0);
        accR[fm][fn] = __builtin_amdgcn_mfma_f32_16x16x32_f16(aA, bB[fn], accR[fm][fn], 0, 0, 0);
      }
    }
    __syncthreads();
  }

  // epilogue: C/D row = kg*4 + r, col = lane&15 (same recombine as rounds 4-7)
#pragma unroll
  for (int fm = 0; fm < 4; ++fm) {
    const int mb = rowBase + wm * 64 + fm * 16 + kg * 4;
#pragma unroll
    for (int fn = 0; fn < 4; ++fn) {
      const int n = colBase + wn * 64 + fn * 16 + col;
      const float bv = bias[n];
#pragma unroll
      for (int r = 0; r < 4; ++r) {
        const float val = accM[fm][fn][r] * 0.015625f
                        + accR[fm][fn][r] * 3.814697265625e-6f + bv;
        C[(size_t)(mb + r) * D + n] = tanhf(val);
      }
    }
  }
}

// ---------------- Kernel B: Z = l2norm(H1 @ W2 + b2), split-K x4 ----------------
// Block = 16 rows x 4 k-quarter waves (4096 waves total = 4/SIMD). Partials
// combined in LDS in fixed order q0+q1+q2+q3.
__global__ __launch_bounds__(256) void gemm2_mfma(
    const float* __restrict__ H, const _Float16* __restrict__ W2Th,
    const _Float16* __restrict__ W2Tr, const float* __restrict__ b2,
    float* __restrict__ Z)
{
  __shared__ float comb[3][64][20];
  const int t = threadIdx.x;
  const int lane = t & 63, kq = t >> 6;
  const int rowBase = blockIdx.x * 16;
  const int col = lane & 15;
  const int kg = lane >> 4;

  const float* Hp = H + (size_t)(rowBase + col) * D + kg * 8;
  const _Float16* WhP[2];
  const _Float16* WrP[2];
#pragma unroll
  for (int fn = 0; fn < 2; ++fn) {
    WhP[fn] = W2Th + (size_t)(fn * 16 + col) * D + kg * 8;
    WrP[fn] = W2Tr + (size_t)(fn * 16 + col) * D + kg * 8;
  }

  f32x4 accM[2], accR[2];
  const f32x4 z4 = {0.f, 0.f, 0.f, 0.f};
  accM[0] = z4; accM[1] = z4; accR[0] = z4; accR[1] = z4;

#pragma unroll 2
  for (int ks = kq * 6; ks < kq * 6 + 6; ++ks) {
    const int ko = ks * 32;
    half8 wA[2], wB[2];
#pragma unroll
    for (int fn = 0; fn < 2; ++fn) {
      wA[fn] = *(const half8*)(WhP[fn] + ko);
      wB[fn] = *(const half8*)(WrP[fn] + ko);
    }
    half8 hA, hB;
    {
      const float4 x0 = *(const float4*)(Hp + ko);
      const float4 x1 = *(const float4*)(Hp + ko + 4);
      const float v[8] = {x0.x, x0.y, x0.z, x0.w, x1.x, x1.y, x1.z, x1.w};
#pragma unroll
      for (int e = 0; e < 8; ++e) {
        const _Float16 h = (_Float16)v[e];
        hA[e] = h;
        hB[e] = (_Float16)((v[e] - (float)h) * 4096.0f);
      }
    }
#pragma unroll
    for (int fn = 0; fn < 2; ++fn) {
      accM[fn] = __builtin_amdgcn_mfma_f32_16x16x32_f16(hA, wA[fn], accM[fn], 0, 0, 0);
      accR[fn] = __builtin_amdgcn_mfma_f32_16x16x32_f16(hB, wA[fn], accR[fn], 0, 0, 0);
      accR[fn] = __builtin_amdgcn_mfma_f32_16x16x32_f16(hA, wB[fn], accR[fn], 0, 0, 0);
    }
  }

  if (kq > 0) {
    float* cp = &comb[kq - 1][lane][0];
    *(f32x4*)(cp)      = accM[0];
    *(f32x4*)(cp + 4)  = accM[1];
    *(f32x4*)(cp + 8)  = accR[0];
    *(f32x4*)(cp + 12) = accR[1];
  }
  __syncthreads();
  if (kq != 0) return;

#pragma unroll
  for (int q = 0; q < 3; ++q) {
    const float* cp = &comb[q][lane][0];
    accM[0] = accM[0] + *(const f32x4*)(cp);
    accM[1] = accM[1] + *(const f32x4*)(cp + 4);
    accR[0] = accR[0] + *(const f32x4*)(cp + 8);
    accR[1] = accR[1] + *(const f32x4*)(cp + 12);
  }

  const float b0 = b2[col], b1 = b2[col + 16];
  float v0[4], v1[4];
#pragma unroll
  for (int r = 0; r < 4; ++r) {
    v0[r] = accM[0][r] * 0.015625f + accR[0][r] * 3.814697265625e-6f + b0;
    v1[r] = accM[1][r] * 0.015625f + accR[1][r] * 3.814697265625e-6f + b1;
  }
#pragma unroll
  for (int r = 0; r < 4; ++r) {
    float ss = v0[r] * v0[r] + v1[r] * v1[r];
    ss += __shfl_xor(ss, 1, 16);
    ss += __shfl_xor(ss, 2, 16);
    ss += __shfl_xor(ss, 4, 16);
    ss += __shfl_xor(ss, 8, 16);
    const float inv = 1.0f / fmaxf(sqrtf(ss), 1e-12f);
    const int row = rowBase + kg * 4 + r;
    Z[(size_t)row * E + col]      = v0[r] * inv;
    Z[(size_t)row * E + col + 16] = v1[r] * inv;
  }
}

// ---------------- Kernel C: VQ argmin via MFMA + gather + STE + per-row loss ----------------
__global__ __launch_bounds__(512) void vq_mfma(
    const float* __restrict__ Z, const float* __restrict__ CB,
    const _Float16* __restrict__ CBh, const _Float16* __restrict__ CBr,
    const float* __restrict__ ccg, float* __restrict__ zq_out,
    float* __restrict__ idx_out, float* __restrict__ lossp)
{
  __shared__ float bDs[64][4];
  __shared__ int   bIs[64][4];

  const int t = threadIdx.x;
  const int lane = t & 63, wave = t >> 6;
  const int mh = wave & 1;
  const int cq = wave >> 1;
  const int rowBase = blockIdx.x * 64;
  const int col = lane & 15, kg = lane >> 4;

  half8 zh[2], zr[2];
#pragma unroll
  for (int mt = 0; mt < 2; ++mt) {
    const float* zp = Z + (size_t)(rowBase + mh * 32 + mt * 16 + col) * E + kg * 8;
    const float4 a = *(const float4*)zp;
    const float4 b = *(const float4*)(zp + 4);
    const float v[8] = {a.x, a.y, a.z, a.w, b.x, b.y, b.z, b.w};
#pragma unroll
    for (int e = 0; e < 8; ++e) {
      const _Float16 h = (_Float16)v[e];
      zh[mt][e] = h;
      zr[mt][e] = (_Float16)((v[e] - (float)h) * 4096.0f);
    }
  }

  const f32x4 zero4 = {0.f, 0.f, 0.f, 0.f};
  float best[2][4];
  int bi[2][4];
#pragma unroll
  for (int mt = 0; mt < 2; ++mt)
#pragma unroll
    for (int r = 0; r < 4; ++r) { best[mt][r] = 3.4e38f; bi[mt][r] = 0; }

  const _Float16* ph = CBh + ((size_t)(cq * 2048 + col) * E + kg * 8);
  const _Float16* pr = CBr + ((size_t)(cq * 2048 + col) * E + kg * 8);
  const float* pc = ccg + cq * 2048 + col;
  int curIdx = cq * 2048 + col;

  for (int tt = 0; tt < 128; ++tt) {
    const half8 bh = *(const half8*)ph;
    const half8 br = *(const half8*)pr;
    const float ccv = *pc;
    ph += 16 * E; pr += 16 * E; pc += 16;
#pragma unroll
    for (int mt = 0; mt < 2; ++mt) {
      f32x4 aM = __builtin_amdgcn_mfma_f32_16x16x32_f16(zh[mt], bh, zero4, 0, 0, 0);
      f32x4 aR = __builtin_amdgcn_mfma_f32_16x16x32_f16(zr[mt], bh, zero4, 0, 0, 0);
      aR = __builtin_amdgcn_mfma_f32_16x16x32_f16(zh[mt], br, aR, 0, 0, 0);
#pragma unroll
      for (int r = 0; r < 4; ++r) {
        const float u = fmaf(aR[r], 2.44140625e-4f, aM[r]);
        const float d = fmaf(u, -2.0f, ccv);
        if (d < best[mt][r]) { best[mt][r] = d; bi[mt][r] = curIdx; }
      }
    }
    curIdx += 16;
  }

#pragma unroll
  for (int m = 1; m <= 8; m <<= 1) {
#pragma unroll
    for (int mt = 0; mt < 2; ++mt)
#pragma unroll
      for (int r = 0; r < 4; ++r) {
        const float ob = __shfl_xor(best[mt][r], m, 64);
        const int   oi = __shfl_xor(bi[mt][r],   m, 64);
        if (ob < best[mt][r] || (ob == best[mt][r] && oi < bi[mt][r])) {
          best[mt][r] = ob; bi[mt][r] = oi;
        }
      }
  }

  if (col == 0) {
#pragma unroll
    for (int mt = 0; mt < 2; ++mt)
#pragma unroll
      for (int r = 0; r < 4; ++r) {
        const int rl = mh * 32 + mt * 16 + kg * 4 + r;
        bDs[rl][cq] = best[mt][r];
        bIs[rl][cq] = bi[mt][r];
      }
  }
  __syncthreads();

  const int rl = t >> 3, part = t & 7;
  float bd = bDs[rl][0];
  int bidx = bIs[rl][0];
#pragma unroll
  for (int q = 1; q < 4; ++q)
    if (bDs[rl][q] < bd) { bd = bDs[rl][q]; bidx = bIs[rl][q]; }

  const int row = rowBase + rl;
  const float4 c4 = *(const float4*)&CB[(size_t)bidx * E + part * 4];
  const float4 z4v = *(const float4*)&Z[(size_t)row * E + part * 4];
  const float dx = c4.x - z4v.x, dy = c4.y - z4v.y;
  const float dz = c4.z - z4v.z, dw = c4.w - z4v.w;
  *(float4*)&zq_out[(size_t)row * E + part * 4] =
      make_float4(z4v.x + dx, z4v.y + dy, z4v.z + dz, z4v.w + dw);
  float ls = dx * dx;
  ls += dy * dy; ls += dz * dz; ls += dw * dw;
  ls += __shfl_xor(ls, 1, 8);
  ls += __shfl_xor(ls, 2, 8);
  ls += __shfl_xor(ls, 4, 8);
  if (part == 0) {
    lossp[row] = ls;
    idx_out[row] = (float)bidx;
  }
}

// ---------------- Kernel D: loss = sum(lossp) / (M*E) ----------------
__global__ __launch_bounds__(256) void loss_reduce(const float* __restrict__ lossp, float* __restrict__ out)
{
  float s = 0.f;
  const float4* p = reinterpret_cast<const float4*>(lossp);
  for (int i = threadIdx.x; i < M / 4; i += 256) {
    float4 v = p[i];
    s += v.x + v.y + v.z + v.w;
  }
#pragma unroll
  for (int m = 32; m >= 1; m >>= 1) s += __shfl_xor(s, m, 64);
  __shared__ float red[4];
  if ((threadIdx.x & 63) == 0) red[threadIdx.x >> 6] = s;
  __syncthreads();
  if (threadIdx.x == 0)
    out[0] = (red[0] + red[1] + red[2] + red[3]) * (1.0f / (float)(M * E));
}

extern "C" void kernel_launch(void* const* d_in, const int* in_sizes, int n_in,
                              void* d_out, int out_size, void* d_ws, size_t ws_size,
                              hipStream_t stream)
{
  const float* X  = (const float*)d_in[0];
  const float* W1 = (const float*)d_in[1];
  const float* b1 = (const float*)d_in[2];
  const float* W2 = (const float*)d_in[3];
  const float* b2 = (const float*)d_in[4];
  const float* CB = (const float*)d_in[5];

  float* out  = (float*)d_out;
  float* zq   = out;
  float* loss = out + 524288;
  float* idxf = out + 524289;

  char* ws = (char*)d_ws;
  float* H1 = (float*)ws;                                  // 48 MB
  float* Z  = (float*)(ws + (size_t)M * D * 4);            // 2 MB
  float* cc = Z + (size_t)M * E;                           // 32 KB
  float* lp = cc + K;                                      // 64 KB
  _Float16* W1aT = (_Float16*)(lp + M);                    // 1.125 MB
  _Float16* W1bT = W1aT + (size_t)D * D;                   // 1.125 MB
  _Float16* CBh  = W1bT + (size_t)D * D;                   // 512 KB
  _Float16* CBr  = CBh + (size_t)K * E;                    // 512 KB
  _Float16* W2Th = CBr + (size_t)K * E;                    // 48 KB
  _Float16* W2Tr = W2Th + (size_t)E * D;                   // 48 KB

  split_w1t<<<dim3(D / 32, D / 32), 256, 0, stream>>>(W1, W1aT, W1bT);
  split_w2t<<<dim3(D * E / 256), 256, 0, stream>>>(W2, W2Th, W2Tr);
  cb_prep<<<dim3(K / 256), 256, 0, stream>>>(CB, cc, CBh, CBr);
  gemm1_mfma<<<dim3(D / 128, M / 128), 256, 0, stream>>>(X, W1aT, W1bT, b1, H1);
  gemm2_mfma<<<dim3(M / 16), 256, 0, stream>>>(H1, W2Th, W2Tr, b2, Z);
  vq_mfma<<<dim3(M / 64), 512, 0, stream>>>(Z, CB, CBh, CBr, cc, zq, idxf, lp);
  loss_reduce<<<1, 256, 0, stream>>>(lp, loss);
}

// Round 10
// 294.070 us; speedup vs baseline: 1.2680x; 1.0088x over previous
//
#include <hip/hip_runtime.h>
#include <cstdint>

static constexpr int M = 16384;   // B*N rows
static constexpr int D = 768;     // feature dim
static constexpr int E = 32;      // code dim
static constexpr int K = 8192;    // codebook size

typedef _Float16 half8 __attribute__((ext_vector_type(8)));
typedef float f32x4 __attribute__((ext_vector_type(4)));

typedef __attribute__((address_space(1))) const uint32_t gu32;
typedef __attribute__((address_space(3))) uint32_t lu32;
__device__ __forceinline__ void g2l16(const void* g, void* l) {
  __builtin_amdgcn_global_load_lds((gu32*)g, (lu32*)l, 16, 0, 0);
}

// ---------------- Pre-pass: W1 [768k][768n] fp32 -> W1aT/W1bT [768n][768k] fp16 ----------------
__global__ __launch_bounds__(256) void split_w1t(const float* __restrict__ W1,
    _Float16* __restrict__ W1aT, _Float16* __restrict__ W1bT)
{
  __shared__ float tile[32][33];
  const int tx = threadIdx.x & 31, ty = threadIdx.x >> 5;
  const int kb = blockIdx.x * 32, nb = blockIdx.y * 32;
#pragma unroll
  for (int i = 0; i < 4; ++i)
    tile[ty * 4 + i][tx] = W1[(size_t)(kb + ty * 4 + i) * 768 + nb + tx];
  __syncthreads();
#pragma unroll
  for (int i = 0; i < 4; ++i) {
    const int n = nb + ty * 4 + i, k = kb + tx;
    const float v = tile[tx][ty * 4 + i] * 64.0f;
    const _Float16 h = (_Float16)v;
    W1aT[(size_t)n * 768 + k] = h;
    W1bT[(size_t)n * 768 + k] = (_Float16)((v - (float)h) * 4096.0f);
  }
}

// ---------------- Pre-pass: W2 [768k][32n] fp32 -> W2Th/W2Tr [32n][768k] fp16 ----------------
__global__ __launch_bounds__(256) void split_w2t(const float* __restrict__ W2,
    _Float16* __restrict__ W2Th, _Float16* __restrict__ W2Tr)
{
  const int i = blockIdx.x * 256 + threadIdx.x;
  const int k = i >> 5, n = i & 31;
  const float v = W2[(size_t)k * 32 + n] * 64.0f;
  const _Float16 h = (_Float16)v;
  W2Th[(size_t)n * 768 + k] = h;
  W2Tr[(size_t)n * 768 + k] = (_Float16)((v - (float)h) * 4096.0f);
}

// ---------------- Pre-pass: codebook -> cc norms + f16 hi/res split ----------------
__global__ __launch_bounds__(256) void cb_prep(const float* __restrict__ CB,
    float* __restrict__ cc, _Float16* __restrict__ CBh, _Float16* __restrict__ CBr)
{
  const int k = blockIdx.x * 256 + threadIdx.x;
  const float4* p = (const float4*)(CB + (size_t)k * E);
  _Float16 hb[32], rb[32];
  float s = 0.f;
#pragma unroll
  for (int q = 0; q < 8; ++q) {
    float4 v = p[q];
    const float e[4] = {v.x, v.y, v.z, v.w};
#pragma unroll
    for (int j = 0; j < 4; ++j) {
      s += e[j] * e[j];
      const _Float16 h = (_Float16)e[j];
      hb[q * 4 + j] = h;
      rb[q * 4 + j] = (_Float16)((e[j] - (float)h) * 4096.0f);
    }
  }
  cc[k] = s;
#pragma unroll
  for (int q = 0; q < 4; ++q) {
    *(half8*)(CBh + (size_t)k * E + q * 8) = *(half8*)&hb[q * 8];
    *(half8*)(CBr + (size_t)k * E + q * 8) = *(half8*)&rb[q * 8];
  }
}

// ---------------- Kernel A: H1 = tanh(X @ W1 + b1) ----------------
// 128x128 tile, 4 waves (2x2 of 64x64). X fp32 via global_load_lds with 8-slot
// XOR source-swizzle (conflict-free ds_read_b128), double-buffered. B (W1
// splits, L2-resident) software-pipelined into REGISTERS one K-step ahead so
// the barrier drain lands during compute. Grid row-fastest (r5-proven FETCH).
// MFMA order per acc identical to rounds 4-8 -> H1 bit-identical.
__global__ __launch_bounds__(256, 2) void gemm1_mfma(
    const float* __restrict__ X, const _Float16* __restrict__ Bag,
    const _Float16* __restrict__ Bbg, const float* __restrict__ bias,
    float* __restrict__ C)
{
  __shared__ __align__(16) float Xs[2][128 * 32];   // 16KB per buffer

  const int t = threadIdx.x;
  const int lane = t & 63, wave = t >> 6;
  const int wm = wave >> 1, wn = wave & 1;
  const int rowBase = blockIdx.x * 128;   // row-fastest grid
  const int colBase = blockIdx.y * 128;
  const int col = lane & 15;
  const int kg = lane >> 4;

  // A staging: 1024 units of 16B (128 rows x 8 slots); 4 g2l16 per thread.
  // source slot pre-swizzled: content(row, s) = X[row][(s ^ (row&7))*4 ..+4]
  const float* srcB[4];
  int dstOff[4];
#pragma unroll
  for (int i = 0; i < 4; ++i) {
    const int u = t + i * 256;
    const int row = u >> 3, slotL = u & 7;
    const int srcSlot = slotL ^ (row & 7);
    srcB[i] = X + (size_t)(rowBase + row) * D + srcSlot * 4;
    dstOff[i] = (i * 256 + wave * 64) * 16;
  }

  const _Float16* BhP[4];
  const _Float16* BrP[4];
#pragma unroll
  for (int fn = 0; fn < 4; ++fn) {
    const int cb = colBase + wn * 64 + fn * 16 + col;
    BhP[fn] = Bag + (size_t)cb * D + kg * 8;
    BrP[fn] = Bbg + (size_t)cb * D + kg * 8;
  }

  // A fragment read offsets (bytes)
  const int swz = lane & 7;
  int aOff0[4], aOff1[4];
#pragma unroll
  for (int fm = 0; fm < 4; ++fm) {
    const int r = wm * 64 + fm * 16 + col;
    aOff0[fm] = r * 128 + ((2 * kg) ^ swz) * 16;
    aOff1[fm] = r * 128 + ((2 * kg + 1) ^ swz) * 16;
  }

  f32x4 accM[4][4], accR[4][4];
  const f32x4 z4 = {0.f, 0.f, 0.f, 0.f};
#pragma unroll
  for (int i = 0; i < 4; ++i)
#pragma unroll
    for (int j = 0; j < 4; ++j) { accM[i][j] = z4; accR[i][j] = z4; }

  half8 bAc[4], bBc[4];

  { // prologue: stage A ks=0; load B frags ks=0 into regs
#pragma unroll
    for (int i = 0; i < 4; ++i)
      g2l16(srcB[i], (char*)&Xs[0][0] + dstOff[i]);
#pragma unroll
    for (int fn = 0; fn < 4; ++fn) {
      bAc[fn] = *(const half8*)(BhP[fn]);
      bBc[fn] = *(const half8*)(BrP[fn]);
    }
    __syncthreads();
  }

  for (int ks = 0; ks < 24; ++ks) {
    const int cur = ks & 1;
    const bool pre = (ks < 23);
    half8 bAn[4], bBn[4];
    if (pre) {
      const int k1 = (ks + 1) * 32;
#pragma unroll
      for (int i = 0; i < 4; ++i)
        g2l16(srcB[i] + k1, (char*)&Xs[cur ^ 1][0] + dstOff[i]);
#pragma unroll
      for (int fn = 0; fn < 4; ++fn) {
        bAn[fn] = *(const half8*)(BhP[fn] + k1);
        bBn[fn] = *(const half8*)(BrP[fn] + k1);
      }
    }
    // A fragments: ds_read fp32 + in-reg split, then MFMA (same per-acc order)
    const char* base = (const char*)&Xs[cur][0];
#pragma unroll
    for (int fm = 0; fm < 4; ++fm) {
      const float4 fa = *(const float4*)(base + aOff0[fm]);
      const float4 fb = *(const float4*)(base + aOff1[fm]);
      const float v[8] = {fa.x, fa.y, fa.z, fa.w, fb.x, fb.y, fb.z, fb.w};
      half8 aA, aB;
#pragma unroll
      for (int e = 0; e < 8; ++e) {
        const _Float16 h = (_Float16)v[e];
        aA[e] = h;
        aB[e] = (_Float16)((v[e] - (float)h) * 4096.0f);
      }
#pragma unroll
      for (int fn = 0; fn < 4; ++fn) {
        accM[fm][fn] = __builtin_amdgcn_mfma_f32_16x16x32_f16(aA, bAc[fn], accM[fm][fn], 0, 0, 0);
        accR[fm][fn] = __builtin_amdgcn_mfma_f32_16x16x32_f16(aB, bAc[fn], accR[fm][fn], 0, 0, 0);
        accR[fm][fn] = __builtin_amdgcn_mfma_f32_16x16x32_f16(aA, bBc[fn], accR[fm][fn], 0, 0, 0);
      }
    }
    __syncthreads();
    if (pre) {
#pragma unroll
      for (int fn = 0; fn < 4; ++fn) { bAc[fn] = bAn[fn]; bBc[fn] = bBn[fn]; }
    }
  }

  // epilogue: same recombine as rounds 4-8
#pragma unroll
  for (int fm = 0; fm < 4; ++fm) {
    const int mb = rowBase + wm * 64 + fm * 16 + kg * 4;
#pragma unroll
    for (int fn = 0; fn < 4; ++fn) {
      const int n = colBase + wn * 64 + fn * 16 + col;
      const float bv = bias[n];
#pragma unroll
      for (int r = 0; r < 4; ++r) {
        const float val = accM[fm][fn][r] * 0.015625f
                        + accR[fm][fn][r] * 3.814697265625e-6f + bv;
        C[(size_t)(mb + r) * D + n] = tanhf(val);
      }
    }
  }
}

// ---------------- Kernel B: Z = l2norm(H1 @ W2 + b2), split-K x4 ----------------
__global__ __launch_bounds__(256) void gemm2_mfma(
    const float* __restrict__ H, const _Float16* __restrict__ W2Th,
    const _Float16* __restrict__ W2Tr, const float* __restrict__ b2,
    float* __restrict__ Z)
{
  __shared__ float comb[3][64][20];
  const int t = threadIdx.x;
  const int lane = t & 63, kq = t >> 6;
  const int rowBase = blockIdx.x * 16;
  const int col = lane & 15;
  const int kg = lane >> 4;

  const float* Hp = H + (size_t)(rowBase + col) * D + kg * 8;
  const _Float16* WhP[2];
  const _Float16* WrP[2];
#pragma unroll
  for (int fn = 0; fn < 2; ++fn) {
    WhP[fn] = W2Th + (size_t)(fn * 16 + col) * D + kg * 8;
    WrP[fn] = W2Tr + (size_t)(fn * 16 + col) * D + kg * 8;
  }

  f32x4 accM[2], accR[2];
  const f32x4 z4 = {0.f, 0.f, 0.f, 0.f};
  accM[0] = z4; accM[1] = z4; accR[0] = z4; accR[1] = z4;

#pragma unroll 2
  for (int ks = kq * 6; ks < kq * 6 + 6; ++ks) {
    const int ko = ks * 32;
    half8 wA[2], wB[2];
#pragma unroll
    for (int fn = 0; fn < 2; ++fn) {
      wA[fn] = *(const half8*)(WhP[fn] + ko);
      wB[fn] = *(const half8*)(WrP[fn] + ko);
    }
    half8 hA, hB;
    {
      const float4 x0 = *(const float4*)(Hp + ko);
      const float4 x1 = *(const float4*)(Hp + ko + 4);
      const float v[8] = {x0.x, x0.y, x0.z, x0.w, x1.x, x1.y, x1.z, x1.w};
#pragma unroll
      for (int e = 0; e < 8; ++e) {
        const _Float16 h = (_Float16)v[e];
        hA[e] = h;
        hB[e] = (_Float16)((v[e] - (float)h) * 4096.0f);
      }
    }
#pragma unroll
    for (int fn = 0; fn < 2; ++fn) {
      accM[fn] = __builtin_amdgcn_mfma_f32_16x16x32_f16(hA, wA[fn], accM[fn], 0, 0, 0);
      accR[fn] = __builtin_amdgcn_mfma_f32_16x16x32_f16(hB, wA[fn], accR[fn], 0, 0, 0);
      accR[fn] = __builtin_amdgcn_mfma_f32_16x16x32_f16(hA, wB[fn], accR[fn], 0, 0, 0);
    }
  }

  if (kq > 0) {
    float* cp = &comb[kq - 1][lane][0];
    *(f32x4*)(cp)      = accM[0];
    *(f32x4*)(cp + 4)  = accM[1];
    *(f32x4*)(cp + 8)  = accR[0];
    *(f32x4*)(cp + 12) = accR[1];
  }
  __syncthreads();
  if (kq != 0) return;

#pragma unroll
  for (int q = 0; q < 3; ++q) {
    const float* cp = &comb[q][lane][0];
    accM[0] = accM[0] + *(const f32x4*)(cp);
    accM[1] = accM[1] + *(const f32x4*)(cp + 4);
    accR[0] = accR[0] + *(const f32x4*)(cp + 8);
    accR[1] = accR[1] + *(const f32x4*)(cp + 12);
  }

  const float b0 = b2[col], b1 = b2[col + 16];
  float v0[4], v1[4];
#pragma unroll
  for (int r = 0; r < 4; ++r) {
    v0[r] = accM[0][r] * 0.015625f + accR[0][r] * 3.814697265625e-6f + b0;
    v1[r] = accM[1][r] * 0.015625f + accR[1][r] * 3.814697265625e-6f + b1;
  }
#pragma unroll
  for (int r = 0; r < 4; ++r) {
    float ss = v0[r] * v0[r] + v1[r] * v1[r];
    ss += __shfl_xor(ss, 1, 16);
    ss += __shfl_xor(ss, 2, 16);
    ss += __shfl_xor(ss, 4, 16);
    ss += __shfl_xor(ss, 8, 16);
    const float inv = 1.0f / fmaxf(sqrtf(ss), 1e-12f);
    const int row = rowBase + kg * 4 + r;
    Z[(size_t)row * E + col]      = v0[r] * inv;
    Z[(size_t)row * E + col + 16] = v1[r] * inv;
  }
}

// ---------------- Kernel C: VQ argmin via MFMA + gather + STE + per-row loss ----------------
__global__ __launch_bounds__(512) void vq_mfma(
    const float* __restrict__ Z, const float* __restrict__ CB,
    const _Float16* __restrict__ CBh, const _Float16* __restrict__ CBr,
    const float* __restrict__ ccg, float* __restrict__ zq_out,
    float* __restrict__ idx_out, float* __restrict__ lossp)
{
  __shared__ float bDs[64][4];
  __shared__ int   bIs[64][4];

  const int t = threadIdx.x;
  const int lane = t & 63, wave = t >> 6;
  const int mh = wave & 1;
  const int cq = wave >> 1;
  const int rowBase = blockIdx.x * 64;
  const int col = lane & 15, kg = lane >> 4;

  half8 zh[2], zr[2];
#pragma unroll
  for (int mt = 0; mt < 2; ++mt) {
    const float* zp = Z + (size_t)(rowBase + mh * 32 + mt * 16 + col) * E + kg * 8;
    const float4 a = *(const float4*)zp;
    const float4 b = *(const float4*)(zp + 4);
    const float v[8] = {a.x, a.y, a.z, a.w, b.x, b.y, b.z, b.w};
#pragma unroll
    for (int e = 0; e < 8; ++e) {
      const _Float16 h = (_Float16)v[e];
      zh[mt][e] = h;
      zr[mt][e] = (_Float16)((v[e] - (float)h) * 4096.0f);
    }
  }

  const f32x4 zero4 = {0.f, 0.f, 0.f, 0.f};
  float best[2][4];
  int bi[2][4];
#pragma unroll
  for (int mt = 0; mt < 2; ++mt)
#pragma unroll
    for (int r = 0; r < 4; ++r) { best[mt][r] = 3.4e38f; bi[mt][r] = 0; }

  const _Float16* ph = CBh + ((size_t)(cq * 2048 + col) * E + kg * 8);
  const _Float16* pr = CBr + ((size_t)(cq * 2048 + col) * E + kg * 8);
  const float* pc = ccg + cq * 2048 + col;
  int curIdx = cq * 2048 + col;

  for (int tt = 0; tt < 128; ++tt) {
    const half8 bh = *(const half8*)ph;
    const half8 br = *(const half8*)pr;
    const float ccv = *pc;
    ph += 16 * E; pr += 16 * E; pc += 16;
#pragma unroll
    for (int mt = 0; mt < 2; ++mt) {
      f32x4 aM = __builtin_amdgcn_mfma_f32_16x16x32_f16(zh[mt], bh, zero4, 0, 0, 0);
      f32x4 aR = __builtin_amdgcn_mfma_f32_16x16x32_f16(zr[mt], bh, zero4, 0, 0, 0);
      aR = __builtin_amdgcn_mfma_f32_16x16x32_f16(zh[mt], br, aR, 0, 0, 0);
#pragma unroll
      for (int r = 0; r < 4; ++r) {
        const float u = fmaf(aR[r], 2.44140625e-4f, aM[r]);
        const float d = fmaf(u, -2.0f, ccv);
        if (d < best[mt][r]) { best[mt][r] = d; bi[mt][r] = curIdx; }
      }
    }
    curIdx += 16;
  }

#pragma unroll
  for (int m = 1; m <= 8; m <<= 1) {
#pragma unroll
    for (int mt = 0; mt < 2; ++mt)
#pragma unroll
      for (int r = 0; r < 4; ++r) {
        const float ob = __shfl_xor(best[mt][r], m, 64);
        const int   oi = __shfl_xor(bi[mt][r],   m, 64);
        if (ob < best[mt][r] || (ob == best[mt][r] && oi < bi[mt][r])) {
          best[mt][r] = ob; bi[mt][r] = oi;
        }
      }
  }

  if (col == 0) {
#pragma unroll
    for (int mt = 0; mt < 2; ++mt)
#pragma unroll
      for (int r = 0; r < 4; ++r) {
        const int rl = mh * 32 + mt * 16 + kg * 4 + r;
        bDs[rl][cq] = best[mt][r];
        bIs[rl][cq] = bi[mt][r];
      }
  }
  __syncthreads();

  const int rl = t >> 3, part = t & 7;
  float bd = bDs[rl][0];
  int bidx = bIs[rl][0];
#pragma unroll
  for (int q = 1; q < 4; ++q)
    if (bDs[rl][q] < bd) { bd = bDs[rl][q]; bidx = bIs[rl][q]; }

  const int row = rowBase + rl;
  const float4 c4 = *(const float4*)&CB[(size_t)bidx * E + part * 4];
  const float4 z4v = *(const float4*)&Z[(size_t)row * E + part * 4];
  const float dx = c4.x - z4v.x, dy = c4.y - z4v.y;
  const float dz = c4.z - z4v.z, dw = c4.w - z4v.w;
  *(float4*)&zq_out[(size_t)row * E + part * 4] =
      make_float4(z4v.x + dx, z4v.y + dy, z4v.z + dz, z4v.w + dw);
  float ls = dx * dx;
  ls += dy * dy; ls += dz * dz; ls += dw * dw;
  ls += __shfl_xor(ls, 1, 8);
  ls += __shfl_xor(ls, 2, 8);
  ls += __shfl_xor(ls, 4, 8);
  if (part == 0) {
    lossp[row] = ls;
    idx_out[row] = (float)bidx;
  }
}

// ---------------- Kernel D: loss = sum(lossp) / (M*E) ----------------
__global__ __launch_bounds__(256) void loss_reduce(const float* __restrict__ lossp, float* __restrict__ out)
{
  float s = 0.f;
  const float4* p = reinterpret_cast<const float4*>(lossp);
  for (int i = threadIdx.x; i < M / 4; i += 256) {
    float4 v = p[i];
    s += v.x + v.y + v.z + v.w;
  }
#pragma unroll
  for (int m = 32; m >= 1; m >>= 1) s += __shfl_xor(s, m, 64);
  __shared__ float red[4];
  if ((threadIdx.x & 63) == 0) red[threadIdx.x >> 6] = s;
  __syncthreads();
  if (threadIdx.x == 0)
    out[0] = (red[0] + red[1] + red[2] + red[3]) * (1.0f / (float)(M * E));
}

extern "C" void kernel_launch(void* const* d_in, const int* in_sizes, int n_in,
                              void* d_out, int out_size, void* d_ws, size_t ws_size,
                              hipStream_t stream)
{
  const float* X  = (const float*)d_in[0];
  const float* W1 = (const float*)d_in[1];
  const float* b1 = (const float*)d_in[2];
  const float* W2 = (const float*)d_in[3];
  const float* b2 = (const float*)d_in[4];
  const float* CB = (const float*)d_in[5];

  float* out  = (float*)d_out;
  float* zq   = out;
  float* loss = out + 524288;
  float* idxf = out + 524289;

  char* ws = (char*)d_ws;
  float* H1 = (float*)ws;                                  // 48 MB
  float* Z  = (float*)(ws + (size_t)M * D * 4);            // 2 MB
  float* cc = Z + (size_t)M * E;                           // 32 KB
  float* lp = cc + K;                                      // 64 KB
  _Float16* W1aT = (_Float16*)(lp + M);                    // 1.125 MB
  _Float16* W1bT = W1aT + (size_t)D * D;                   // 1.125 MB
  _Float16* CBh  = W1bT + (size_t)D * D;                   // 512 KB
  _Float16* CBr  = CBh + (size_t)K * E;                    // 512 KB
  _Float16* W2Th = CBr + (size_t)K * E;                    // 48 KB
  _Float16* W2Tr = W2Th + (size_t)E * D;                   // 48 KB

  split_w1t<<<dim3(D / 32, D / 32), 256, 0, stream>>>(W1, W1aT, W1bT);
  split_w2t<<<dim3(D * E / 256), 256, 0, stream>>>(W2, W2Th, W2Tr);
  cb_prep<<<dim3(K / 256), 256, 0, stream>>>(CB, cc, CBh, CBr);
  gemm1_mfma<<<dim3(M / 128, D / 128), 256, 0, stream>>>(X, W1aT, W1bT, b1, H1);
  gemm2_mfma<<<dim3(M / 16), 256, 0, stream>>>(H1, W2Th, W2Tr, b2, Z);
  vq_mfma<<<dim3(M / 64), 512, 0, stream>>>(Z, CB, CBh, CBr, cc, zq, idxf, lp);
  loss_reduce<<<1, 256, 0, stream>>>(lp, loss);
}